// Round 4
// baseline (46.667 us; speedup 1.0000x reference)
//
#include <hip/hip_runtime.h>
#include <math.h>

#define IMG 128
#define NPIX (IMG * IMG)
#define NF 1024
#define NCHUNK 8
#define CHF 128                    // faces per chunk
#define NEAR_Z 0.1f
#define NSHADE_BLK 256

struct AllViews { float m[4][12]; };  // per view: xax[3], yax[3], zax[3], eye[3]

__device__ __forceinline__ void project_face(
    const float* __restrict__ verts, const int* __restrict__ faces,
    const float* M, float W, int f, float proj[3][3])
{
#pragma unroll
    for (int k = 0; k < 3; ++k) {
        int vi = faces[f * 3 + k];
        float px = verts[vi * 3 + 0] - M[9];
        float py = verts[vi * 3 + 1] - M[10];
        float pz = verts[vi * 3 + 2] - M[11];
        float x = M[0] * px + M[1] * py + M[2] * pz;
        float y = M[3] * px + M[4] * py + M[5] * pz;
        float z = M[6] * px + M[7] * py + M[8] * pz;
        proj[k][0] = x / (z * W);
        proj[k][1] = y / (z * W);
        proj[k][2] = z;
    }
}

// w1 = a1.p + b1 ; w2 = a2.p + b2 ; depth = dd.p + dc  (affine in screen xy)
__device__ __forceinline__ void face_planes(const float proj[3][3],
    float& a1x, float& a1y, float& b1, float& a2x, float& a2y, float& b2,
    float& ddx, float& ddy, float& dc)
{
    float v0x = proj[0][0], v0y = proj[0][1];
    float e1x = proj[1][0] - v0x, e1y = proj[1][1] - v0y;
    float e2x = proj[2][0] - v0x, e2y = proj[2][1] - v0y;
    float det = e1x * e2y - e1y * e2x;
    bool ok = fabsf(det) > 1e-8f;
    float inv = ok ? 1.0f / det : 0.0f;
    a1x = e2y * inv; a1y = -e2x * inv;
    b1 = -(a1x * v0x + a1y * v0y);
    a2x = -e1y * inv; a2y = e1x * inv;
    b2 = -(a2x * v0x + a2y * v0y);
    float g1 = proj[1][2] - proj[0][2];
    float g2 = proj[2][2] - proj[0][2];
    ddx = g1 * a1x + g2 * a2x;
    ddy = g1 * a1y + g2 * a2y;
    dc  = proj[0][2] + g1 * b1 + g2 * b2;
    if (!ok) dc = 0.0f;   // depth 0 < NEAR -> never visible (matches `ok` mask)
}

// One block per (view, 2-row strip, face-chunk). Threads 0-127 build the
// chunk's face planes + screen bboxes in LDS; then 256 threads (1 pixel each)
// scan 128 faces with an exact wave-uniform bbox cull. No atomics.
__global__ __launch_bounds__(256) void raster(
    const float* __restrict__ verts, const int* __restrict__ faces,
    unsigned long long* __restrict__ keys, AllViews vc, float W)
{
    __shared__ float4 BB[CHF];   // ymin ymax xmin xmax
    __shared__ float4 P0[CHF];   // a1x a1y b1 a2x
    __shared__ float4 P1[CHF];   // a2y b2 ddx ddy
    __shared__ float  DC[CHF];

    int bid = blockIdx.x;
    int view  = bid >> 9;          // 512 blocks per view
    int b     = bid & 511;
    int chunk = b & (NCHUNK - 1);
    int ptile = b >> 3;            // 64 strips of 2 rows
    int tid = threadIdx.x;

    if (tid < CHF) {
        int f = chunk * CHF + tid;
        float proj[3][3];
        project_face(verts, faces, vc.m[view], W, f, proj);
        float a1x, a1y, b1, a2x, a2y, b2, ddx, ddy, dc;
        face_planes(proj, a1x, a1y, b1, a2x, a2y, b2, ddx, ddy, dc);
        P0[tid] = make_float4(a1x, a1y, b1, a2x);
        P1[tid] = make_float4(a2y, b2, ddx, ddy);
        DC[tid] = dc;
        float ymin = fminf(fminf(proj[0][1], proj[1][1]), proj[2][1]);
        float ymax = fmaxf(fmaxf(proj[0][1], proj[1][1]), proj[2][1]);
        float xmin = fminf(fminf(proj[0][0], proj[1][0]), proj[2][0]);
        float xmax = fmaxf(fmaxf(proj[0][0], proj[1][0]), proj[2][0]);
        BB[tid] = make_float4(ymin, ymax, xmin, xmax);
    }
    __syncthreads();

    int p = ptile * 256 + tid;
    int row = p >> 7, col = p & 127;
    float sx = (col + 0.5f) * (2.0f / IMG) - 1.0f;
    float sy = -((row + 0.5f) * (2.0f / IMG) - 1.0f);
    // this wave's x-span (64 consecutive columns: cols 0-63 or 64-127)
    int col0 = tid & 64;
    float wx0 = (col0 + 0.5f) * (2.0f / IMG) - 1.0f;
    float wx1 = (col0 + 63.5f) * (2.0f / IMG) - 1.0f;

    float best = INFINITY;
    int bf = 0;

    for (int f = 0; f < CHF; ++f) {
        float4 bb = BB[f];   // broadcast read
        // exact reject: sample point outside triangle bbox (wave-uniform)
        if (bb.x > sy || bb.y < sy || bb.z > wx1 || bb.w < wx0) continue;
        float4 Q0 = P0[f];
        float4 Q1 = P1[f];
        float dc  = DC[f];
        float w1  = fmaf(Q0.x, sx, fmaf(Q0.y, sy, Q0.z));
        float w2  = fmaf(Q0.w, sx, fmaf(Q1.x, sy, Q1.y));
        float dep = fmaf(Q1.z, sx, fmaf(Q1.w, sy, dc));
        bool vis  = (fminf(w1, w2) >= 0.0f) && (w1 + w2 <= 1.0f) && (dep > NEAR_Z);
        bool take = vis && (dep < best);   // strict < keeps lowest index
        best = take ? dep : best;
        bf   = take ? f : bf;
    }

    unsigned int dbits = __float_as_uint(best);   // inf -> 0x7f800000 sentinel
    unsigned long long key =
        ((unsigned long long)dbits << 32) | (unsigned int)(chunk * CHF + bf);
    keys[((size_t)(view * NCHUNK + chunk) << 14) + p] = key;
}

// One thread per (view, pixel): min over 8 chunk keys, recompute winner's
// planes from verts, trilinear tanh texture, per-block partial loss.
__global__ __launch_bounds__(256) void shade_loss(
    const float* __restrict__ verts, const int* __restrict__ faces,
    const unsigned long long* __restrict__ keys,
    const float* __restrict__ tex,
    const float* __restrict__ refs,
    float* __restrict__ partial, AllViews vc, float W)
{
    __shared__ float wsum[4];
    int t = blockIdx.x * blockDim.x + threadIdx.x;
    int view = t >> 14, p = t & (NPIX - 1);
    int row = p >> 7, col = p & 127;
    float sx = (col + 0.5f) * (2.0f / IMG) - 1.0f;
    float sy = -((row + 0.5f) * (2.0f / IMG) - 1.0f);

    const unsigned long long* kb = keys + ((size_t)(view * NCHUNK) << 14) + p;
    unsigned long long key = ~0ULL;
#pragma unroll
    for (int c = 0; c < NCHUNK; ++c) {
        unsigned long long k = kb[(size_t)c << 14];
        key = (k < key) ? k : key;
    }

    bool hit = (unsigned int)(key >> 32) < 0x7f800000u;
    float ref = refs[t];
    float lossv;
    if (hit) {
        int f = (int)(key & 0xffffffffu);
        float proj[3][3];
        project_face(verts, faces, vc.m[view], W, f, proj);
        float a1x, a1y, b1, a2x, a2y, b2, ddx, ddy, dc;
        face_planes(proj, a1x, a1y, b1, a2x, a2y, b2, ddx, ddy, dc);
        float w1 = fmaf(a1x, sx, fmaf(a1y, sy, b1));
        float w2 = fmaf(a2x, sx, fmaf(a2y, sy, b2));
        float w0 = 1.0f - w1 - w2;
        float cx = fminf(fmaxf(w0, 0.0f), 1.0f) * 3.0f;
        float cy = fminf(fmaxf(w1, 0.0f), 1.0f) * 3.0f;
        float cz = fminf(fmaxf(w2, 0.0f), 1.0f) * 3.0f;
        int ix = min(max((int)floorf(cx), 0), 2);
        int iy = min(max((int)floorf(cy), 0), 2);
        int iz = min(max((int)floorf(cz), 0), 2);
        float fx = cx - (float)ix, fy = cy - (float)iy, fz = cz - (float)iz;

        const float* T = tex + (size_t)f * 192;   // 4*4*4*3
        float c0 = 0.0f, c1 = 0.0f, c2 = 0.0f;
        for (int dxi = 0; dxi < 2; ++dxi)
            for (int dyi = 0; dyi < 2; ++dyi)
                for (int dzi = 0; dzi < 2; ++dzi) {
                    float w = (dxi ? fx : 1.0f - fx) *
                              (dyi ? fy : 1.0f - fy) *
                              (dzi ? fz : 1.0f - fz);
                    int base = (((ix + dxi) * 4 + (iy + dyi)) * 4 + (iz + dzi)) * 3;
                    c0 += w * tanhf(T[base + 0]);
                    c1 += w * tanhf(T[base + 1]);
                    c2 += w * tanhf(T[base + 2]);
                }
        float d0 = c0 - ref, d1 = c1 - ref, d2 = c2 - ref;
        lossv = d0 * d0 + d1 * d1 + d2 * d2;
    } else {
        lossv = 3.0f * ref * ref;
    }

    for (int off = 32; off; off >>= 1) lossv += __shfl_down(lossv, off);
    int tid = threadIdx.x;
    if ((tid & 63) == 0) wsum[tid >> 6] = lossv;
    __syncthreads();
    if (tid == 0) partial[blockIdx.x] = wsum[0] + wsum[1] + wsum[2] + wsum[3];
}

// Single block: sum NSHADE_BLK partials, plain-store the scalar loss.
__global__ __launch_bounds__(256) void final_reduce(
    const float* __restrict__ partial, float* __restrict__ out)
{
    __shared__ float wsum[4];
    int tid = threadIdx.x;
    float v = partial[tid];
    for (int off = 32; off; off >>= 1) v += __shfl_down(v, off);
    if ((tid & 63) == 0) wsum[tid >> 6] = v;
    __syncthreads();
    if (tid == 0) out[0] = wsum[0] + wsum[1] + wsum[2] + wsum[3];
}

static void make_view(double dist, double elev, double azim, float* M)
{
    double e = elev * M_PI / 180.0, a = azim * M_PI / 180.0;
    float ex = (float)(dist * cos(e) * sin(a));
    float ey = (float)(dist * sin(e));
    float ez = (float)(-dist * cos(e) * cos(a));
    float zx = -ex, zy = -ey, zz = -ez;
    float n = sqrtf(zx * zx + zy * zy + zz * zz);
    zx /= n; zy /= n; zz /= n;
    float xx = zz, xy = 0.0f, xz = -zx;
    n = sqrtf(xx * xx + xy * xy + xz * xz);
    xx /= n; xy /= n; xz /= n;
    float yx = zy * xz - zz * xy;
    float yy = zz * xx - zx * xz;
    float yz = zx * xy - zy * xx;
    n = sqrtf(yx * yx + yy * yy + yz * yz);
    yx /= n; yy /= n; yz /= n;
    M[0] = xx; M[1] = xy; M[2] = xz;
    M[3] = yx; M[4] = yy; M[5] = yz;
    M[6] = zx; M[7] = zy; M[8] = zz;
    M[9] = ex; M[10] = ey; M[11] = ez;
}

extern "C" void kernel_launch(void* const* d_in, const int* in_sizes, int n_in,
                              void* d_out, int out_size, void* d_ws, size_t ws_size,
                              hipStream_t stream)
{
    const float* verts = (const float*)d_in[0];
    const int*   faces = (const int*)d_in[1];
    const float* tex   = (const float*)d_in[2];
    const float* refs  = (const float*)d_in[3];
    float* out = (float*)d_out;

    char* ws = (char*)d_ws;
    unsigned long long* keys = (unsigned long long*)ws;  // 4*8*16384*8 = 4 MB
    ws += (size_t)4 * NCHUNK * NPIX * sizeof(unsigned long long);
    float* partial = (float*)ws;                         // 256 floats

    AllViews vc;
    const double V[4][3] = {{2.83, 45.0, 0.0}, {2.0, 0.0, 90.0},
                            {3.46, 45.0, 45.0}, {3.0, 0.0, 0.0}};
    for (int i = 0; i < 4; ++i) make_view(V[i][0], V[i][1], V[i][2], vc.m[i]);
    float W = (float)tan(M_PI / 6.0);

    raster<<<2048, 256, 0, stream>>>(verts, faces, keys, vc, W);
    shade_loss<<<NSHADE_BLK, 256, 0, stream>>>(verts, faces, keys, tex, refs,
                                               partial, vc, W);
    final_reduce<<<1, 256, 0, stream>>>(partial, out);
}

// Round 5
// 44.392 us; speedup vs baseline: 1.0513x; 1.0513x over previous
//
#include <hip/hip_runtime.h>
#include <math.h>

#define IMG 128
#define NPIX (IMG * IMG)
#define NF 1024
#define NCHUNK 8
#define CHF 128
#define NEAR_Z 0.1f
#define DY 0.015625f               // 2/IMG, exact power-of-2 step

struct AllViews { float m[4][12]; };  // per view: xax[3], yax[3], zax[3], eye[3]

__device__ __forceinline__ void project_face(
    const float* __restrict__ verts, const int* __restrict__ faces,
    const float* M, float W, int f, float proj[3][3])
{
#pragma unroll
    for (int k = 0; k < 3; ++k) {
        int vi = faces[f * 3 + k];
        float px = verts[vi * 3 + 0] - M[9];
        float py = verts[vi * 3 + 1] - M[10];
        float pz = verts[vi * 3 + 2] - M[11];
        float x = M[0] * px + M[1] * py + M[2] * pz;
        float y = M[3] * px + M[4] * py + M[5] * pz;
        float z = M[6] * px + M[7] * py + M[8] * pz;
        proj[k][0] = x / (z * W);
        proj[k][1] = y / (z * W);
        proj[k][2] = z;
    }
}

// 6 plane coeffs for w1,w2 + (z0,g1,g2) for depth = z0 + w1*g1 + w2*g2.
__device__ __forceinline__ void face_planes(const float proj[3][3],
    float& a1x, float& a1y, float& b1, float& a2x, float& a2y, float& b2,
    float& z0, float& g1, float& g2)
{
    float v0x = proj[0][0], v0y = proj[0][1];
    float e1x = proj[1][0] - v0x, e1y = proj[1][1] - v0y;
    float e2x = proj[2][0] - v0x, e2y = proj[2][1] - v0y;
    float det = e1x * e2y - e1y * e2x;
    bool ok = fabsf(det) > 1e-8f;
    float inv = ok ? 1.0f / det : 0.0f;
    a1x = e2y * inv; a1y = -e2x * inv;
    b1 = -(a1x * v0x + a1y * v0y);
    a2x = -e1y * inv; a2y = e1x * inv;
    b2 = -(a2x * v0x + a2y * v0y);
    z0 = ok ? proj[0][2] : 0.0f;   // !ok -> depth 0 < NEAR -> invisible
    g1 = proj[1][2] - proj[0][2];
    g2 = proj[2][2] - proj[0][2];
}

__device__ __forceinline__ float fast_tanh(float x)
{
    float xc = fminf(fmaxf(x, -10.0f), 10.0f);
    float e = __expf(2.0f * xc);
    return __fdividef(e - 1.0f, e + 1.0f);
}

// Block = (view, 8-row strip, face-chunk). Build: threads 0-127 project the
// chunk's 128 faces, write 9-float records to LDS, ballot per-2-row-strip
// intersection masks. Scan: wave w owns rows (2w,2w+1); iterates only set
// mask bits; 4 pixels/thread (rows r,r+1 x cols l,l+64).
__global__ __launch_bounds__(256) void raster(
    const float* __restrict__ verts, const int* __restrict__ faces,
    unsigned long long* __restrict__ keys, unsigned int* __restrict__ counter,
    AllViews vc, float W)
{
    __shared__ float4 P0[CHF];                 // a1x a1y b1 a2x
    __shared__ float4 P1[CHF];                 // a2y b2 z0 g1
    __shared__ float  G2[CHF];
    __shared__ unsigned long long MASK[4][2];

    int bid = blockIdx.x;
    int view  = bid >> 7;          // 128 blocks per view
    int b     = bid & 127;
    int chunk = b & (NCHUNK - 1);
    int strip = b >> 3;            // 0..15, 8 rows each
    int tid  = threadIdx.x;
    int wave = tid >> 6, lane = tid & 63;

    if (bid == 0 && tid == 0) *counter = 0;   // reset for shade's last-block

    float ymin = INFINITY, ymax = -INFINITY;
    if (tid < CHF) {
        int f = chunk * CHF + tid;
        float proj[3][3];
        project_face(verts, faces, vc.m[view], W, f, proj);
        float a1x, a1y, b1, a2x, a2y, b2, z0, g1, g2;
        face_planes(proj, a1x, a1y, b1, a2x, a2y, b2, z0, g1, g2);
        P0[tid] = make_float4(a1x, a1y, b1, a2x);
        P1[tid] = make_float4(a2y, b2, z0, g1);
        G2[tid] = g2;
        if (z0 != 0.0f) {   // ok faces only; !ok stays empty bbox -> culled
            ymin = fminf(fminf(proj[0][1], proj[1][1]), proj[2][1]);
            ymax = fmaxf(fmaxf(proj[0][1], proj[1][1]), proj[2][1]);
        }
    }
    if (wave < 2) {
#pragma unroll
        for (int rp = 0; rp < 4; ++rp) {
            int r0 = strip * 8 + 2 * rp;
            float syhi = 1.0f - (r0 + 0.5f) * DY;   // sy of row r0 (exact)
            float sylo = syhi - DY;                 // sy of row r0+1 (exact)
            bool inter = (ymin <= syhi) && (ymax >= sylo);
            unsigned long long m = __ballot(inter);
            if (lane == 0) MASK[rp][wave] = m;
        }
    }
    __syncthreads();

    int r0 = strip * 8 + 2 * wave;
    float sy0 = 1.0f - (r0 + 0.5f) * DY;
    float sx0 = (lane + 0.5f) * DY - 1.0f;      // col = lane; col+64: sx0+1.0

    float bst[4] = {INFINITY, INFINITY, INFINITY, INFINITY};
    int   bfi[4] = {0, 0, 0, 0};

#pragma unroll
    for (int half = 0; half < 2; ++half) {
        unsigned long long m = MASK[wave][half];
        int fbase = half * 64;
        while (m) {
            int f = fbase + (int)__builtin_ctzll(m);
            m &= m - 1;
            float4 q0 = P0[f];
            float4 q1 = P1[f];
            float g2  = G2[f];
            float w1_00 = fmaf(q0.x, sx0, fmaf(q0.y, sy0, q0.z));
            float w2_00 = fmaf(q0.w, sx0, fmaf(q1.x, sy0, q1.y));
            float w1_01 = w1_00 + q0.x;              // sx + 1.0 (exact step)
            float w2_01 = w2_00 + q0.w;
            float w1_10 = fmaf(q0.y, -DY, w1_00);    // row+1
            float w2_10 = fmaf(q1.x, -DY, w2_00);
            float w1_11 = w1_10 + q0.x;
            float w2_11 = w2_10 + q0.w;
            float w1q[4] = {w1_00, w1_01, w1_10, w1_11};
            float w2q[4] = {w2_00, w2_01, w2_10, w2_11};
#pragma unroll
            for (int q = 0; q < 4; ++q) {
                float w1 = w1q[q], w2 = w2q[q];
                float dep = fmaf(w2, g2, fmaf(w1, q1.w, q1.z));
                bool vis = (fminf(w1, w2) >= 0.0f) && (w1 + w2 <= 1.0f) &&
                           (dep > NEAR_Z);
                bool take = vis && (dep < bst[q]);   // strict <: lowest f wins
                bst[q] = take ? dep : bst[q];
                bfi[q] = take ? f : bfi[q];
            }
        }
    }

    size_t base = ((size_t)(view * NCHUNK + chunk) << 14);
    int p00 = r0 * IMG + lane;
    int fo = chunk * CHF;
#pragma unroll
    for (int q = 0; q < 4; ++q) {
        unsigned long long key =
            ((unsigned long long)__float_as_uint(bst[q]) << 32) |
            (unsigned int)(fo + bfi[q]);
        keys[base + p00 + (q & 1) * 64 + (q >> 1) * IMG] = key;
    }
}

// One thread per (view, pixel): min over 8 chunk keys, recompute winner's
// planes, trilinear tanh texture, loss; last block does the final reduce.
__global__ __launch_bounds__(256) void shade_loss(
    const float* __restrict__ verts, const int* __restrict__ faces,
    const unsigned long long* __restrict__ keys,
    const float* __restrict__ tex,
    const float* __restrict__ refs,
    float* __restrict__ partial, unsigned int* __restrict__ counter,
    float* __restrict__ out, AllViews vc, float W)
{
    __shared__ float wsum[4];
    __shared__ bool last;
    int tid = threadIdx.x;
    int t = blockIdx.x * 256 + tid;
    int view = t >> 14, p = t & (NPIX - 1);
    int row = p >> 7, col = p & 127;
    float sx = (col + 0.5f) * DY - 1.0f;
    float sy = 1.0f - (row + 0.5f) * DY;

    const unsigned long long* kb = keys + ((size_t)(view * NCHUNK) << 14) + p;
    unsigned long long key = ~0ULL;
#pragma unroll
    for (int c = 0; c < NCHUNK; ++c) {
        unsigned long long k = kb[(size_t)c << 14];
        key = (k < key) ? k : key;
    }

    bool hit = (unsigned int)(key >> 32) < 0x7f800000u;
    float ref = refs[t];
    float lossv;
    if (hit) {
        int f = (int)(key & 0xffffffffu);
        float proj[3][3];
        project_face(verts, faces, vc.m[view], W, f, proj);
        float a1x, a1y, b1, a2x, a2y, b2, z0, g1, g2;
        face_planes(proj, a1x, a1y, b1, a2x, a2y, b2, z0, g1, g2);
        float w1 = fmaf(a1x, sx, fmaf(a1y, sy, b1));
        float w2 = fmaf(a2x, sx, fmaf(a2y, sy, b2));
        float w0 = 1.0f - w1 - w2;
        float cx = fminf(fmaxf(w0, 0.0f), 1.0f) * 3.0f;
        float cy = fminf(fmaxf(w1, 0.0f), 1.0f) * 3.0f;
        float cz = fminf(fmaxf(w2, 0.0f), 1.0f) * 3.0f;
        int ix = min(max((int)floorf(cx), 0), 2);
        int iy = min(max((int)floorf(cy), 0), 2);
        int iz = min(max((int)floorf(cz), 0), 2);
        float fx = cx - (float)ix, fy = cy - (float)iy, fz = cz - (float)iz;

        const float* T = tex + (size_t)f * 192;   // 4*4*4*3
        float c0 = 0.0f, c1 = 0.0f, c2 = 0.0f;
#pragma unroll
        for (int dxi = 0; dxi < 2; ++dxi)
#pragma unroll
            for (int dyi = 0; dyi < 2; ++dyi)
#pragma unroll
                for (int dzi = 0; dzi < 2; ++dzi) {
                    float w = (dxi ? fx : 1.0f - fx) *
                              (dyi ? fy : 1.0f - fy) *
                              (dzi ? fz : 1.0f - fz);
                    int base = (((ix + dxi) * 4 + (iy + dyi)) * 4 + (iz + dzi)) * 3;
                    c0 += w * fast_tanh(T[base + 0]);
                    c1 += w * fast_tanh(T[base + 1]);
                    c2 += w * fast_tanh(T[base + 2]);
                }
        float d0 = c0 - ref, d1 = c1 - ref, d2 = c2 - ref;
        lossv = d0 * d0 + d1 * d1 + d2 * d2;
    } else {
        lossv = 3.0f * ref * ref;
    }

    for (int off = 32; off; off >>= 1) lossv += __shfl_down(lossv, off);
    if ((tid & 63) == 0) wsum[tid >> 6] = lossv;
    __syncthreads();
    if (tid == 0) {
        partial[blockIdx.x] = wsum[0] + wsum[1] + wsum[2] + wsum[3];
        __threadfence();
        unsigned int old = atomicAdd(counter, 1);
        last = (old == (unsigned int)(gridDim.x - 1));
    }
    __syncthreads();
    if (last) {                       // fixed-order sum -> deterministic
        __threadfence();
        float v = partial[tid];
        for (int off = 32; off; off >>= 1) v += __shfl_down(v, off);
        if ((tid & 63) == 0) wsum[tid >> 6] = v;
        __syncthreads();
        if (tid == 0) out[0] = wsum[0] + wsum[1] + wsum[2] + wsum[3];
    }
}

static void make_view(double dist, double elev, double azim, float* M)
{
    double e = elev * M_PI / 180.0, a = azim * M_PI / 180.0;
    float ex = (float)(dist * cos(e) * sin(a));
    float ey = (float)(dist * sin(e));
    float ez = (float)(-dist * cos(e) * cos(a));
    float zx = -ex, zy = -ey, zz = -ez;
    float n = sqrtf(zx * zx + zy * zy + zz * zz);
    zx /= n; zy /= n; zz /= n;
    float xx = zz, xy = 0.0f, xz = -zx;
    n = sqrtf(xx * xx + xy * xy + xz * xz);
    xx /= n; xy /= n; xz /= n;
    float yx = zy * xz - zz * xy;
    float yy = zz * xx - zx * xz;
    float yz = zx * xy - zy * xx;
    n = sqrtf(yx * yx + yy * yy + yz * yz);
    yx /= n; yy /= n; yz /= n;
    M[0] = xx; M[1] = xy; M[2] = xz;
    M[3] = yx; M[4] = yy; M[5] = yz;
    M[6] = zx; M[7] = zy; M[8] = zz;
    M[9] = ex; M[10] = ey; M[11] = ez;
}

extern "C" void kernel_launch(void* const* d_in, const int* in_sizes, int n_in,
                              void* d_out, int out_size, void* d_ws, size_t ws_size,
                              hipStream_t stream)
{
    const float* verts = (const float*)d_in[0];
    const int*   faces = (const int*)d_in[1];
    const float* tex   = (const float*)d_in[2];
    const float* refs  = (const float*)d_in[3];
    float* out = (float*)d_out;

    char* ws = (char*)d_ws;
    unsigned long long* keys = (unsigned long long*)ws;   // 4*8*16384*8 = 4 MB
    ws += (size_t)4 * NCHUNK * NPIX * sizeof(unsigned long long);
    float* partial = (float*)ws;                          // 256 floats
    ws += 256 * sizeof(float);
    unsigned int* counter = (unsigned int*)ws;            // 4 B

    AllViews vc;
    const double V[4][3] = {{2.83, 45.0, 0.0}, {2.0, 0.0, 90.0},
                            {3.46, 45.0, 45.0}, {3.0, 0.0, 0.0}};
    for (int i = 0; i < 4; ++i) make_view(V[i][0], V[i][1], V[i][2], vc.m[i]);
    float W = (float)tan(M_PI / 6.0);

    raster<<<512, 256, 0, stream>>>(verts, faces, keys, counter, vc, W);
    shade_loss<<<256, 256, 0, stream>>>(verts, faces, keys, tex, refs,
                                        partial, counter, out, vc, W);
}